// Round 15
// baseline (720.829 us; speedup 1.0000x reference)
//
#include <hip/hip_runtime.h>
#include <stdint.h>

#define NTOT 8192
#define BHALF 4096
#define DZ 512
#define DC 128
#define TEMPV 0.5f
#define FIXM 16.0f
#define LOG2E 1.44269504f
#define FM2 23.08312065f   // FIXM * LOG2E
#define SCALE1 0x7F7F7F7F  // e8m0 unit scales

typedef __attribute__((ext_vector_type(4))) float f32x4;
typedef __attribute__((ext_vector_type(4))) float floatx4;
typedef __attribute__((ext_vector_type(2))) unsigned long ulong2v;  // 16B chunk
typedef __attribute__((ext_vector_type(8))) int int8v;              // 32B MFMA operand
typedef __attribute__((ext_vector_type(4))) unsigned int uint4v;

#define MFMAS(a, b, c) \
  __builtin_amdgcn_mfma_scale_f32_16x16x128_f8f6f4((a), (b), (c), 0, 0, 0, SCALE1, 0, SCALE1)

__device__ __forceinline__ uint32_t pk4_e4m3(float f0, float f1, float f2, float f3) {
  int w = 0;
  w = __builtin_amdgcn_cvt_pk_fp8_f32(f0, f1, w, false);
  w = __builtin_amdgcn_cvt_pk_fp8_f32(f2, f3, w, true);
  return (uint32_t)w;
}

__device__ __forceinline__ int8v mk8(ulong2v lo, ulong2v hi) {
  int8v r;
  ((ulong2v*)&r)[0] = lo;
  ((ulong2v*)&r)[1] = hi;
  return r;
}

// ---------------- convert: fp32 -> fp8 e4m3 (frag-pair-tiled) + pos dots + init ----------------
// Blocks 0..1279: 16B chunk ((ct*KP+cc)*64+lane): bytes 0..7 = x[ct*16+ln][cc*64+lq*8..+8),
// bytes 8..15 same +32 in k. A-frag layout == B-frag layout; chunk-pair (2kq,2kq+1) =
// 32B K=128 MFMA operand (consistent k-permutation for A and B -> dot unaffected).
// Blocks 1280..1535: pos2[p] = 2*dot(z_i[p], z_j[p]) exact fp32. Block 1280 also
// zeroes out[0] and inits the 64 group counters to 64 (visible to fused at the
// kernel boundary).
__global__ void convert_kernel(const float* __restrict__ z_i, const float* __restrict__ z_j,
                               const float* __restrict__ c_i, const float* __restrict__ c_j,
                               uint8_t* __restrict__ zbT, uint8_t* __restrict__ cbT,
                               float* __restrict__ pos2, unsigned int* __restrict__ ctr,
                               float* __restrict__ out) {
  const int ZC = NTOT * DZ / 16;   // 262144 chunks
  const int CC = NTOT * DC / 16;   // 65536

  if (blockIdx.x >= 1280) {
    if (blockIdx.x == 1280) {
      if (threadIdx.x == 0) out[0] = 0.0f;
      if (threadIdx.x < 64) ctr[threadIdx.x] = 64u;   // 64 contributors per row-group
    }
    const int wv   = (blockIdx.x - 1280) * 4 + (threadIdx.x >> 6);
    const int lane = threadIdx.x & 63;
#pragma unroll
    for (int q = 0; q < 4; ++q) {
      const int p = wv * 4 + q;
      const float* a = z_i + (size_t)p * DZ + lane * 8;
      const float* b = z_j + (size_t)p * DZ + lane * 8;
      floatx4 a0 = *(const floatx4*)a, a1 = *(const floatx4*)(a + 4);
      floatx4 b0 = *(const floatx4*)b, b1 = *(const floatx4*)(b + 4);
      float d = a0[0]*b0[0] + a0[1]*b0[1] + a0[2]*b0[2] + a0[3]*b0[3]
              + a1[0]*b1[0] + a1[1]*b1[1] + a1[2]*b1[2] + a1[3]*b1[3];
#pragma unroll
      for (int off = 1; off < 64; off <<= 1) d += __shfl_xor(d, off);
      if (lane == 0) pos2[p] = 2.0f * d;
    }
    return;
  }

  int i = blockIdx.x * blockDim.x + threadIdx.x;
  const float* src;
  uint8_t* dst;
  int k0;
  if (i < ZC) {
    int lane = i & 63, g = i >> 6;
    int ct = g >> 3, cc = g & 7;
    int ln = lane & 15, lq = lane >> 4;
    int row = ct * 16 + ln;
    k0 = cc * 64 + lq * 8;
    src = (row < BHALF) ? (z_i + (size_t)row * DZ) : (z_j + (size_t)(row - BHALF) * DZ);
    dst = zbT + (size_t)i * 16;
  } else {
    int i2 = i - ZC;
    int lane = i2 & 63, g = i2 >> 6;
    int ct = g >> 1, cc = g & 1;
    int ln = lane & 15, lq = lane >> 4;
    int row = ct * 16 + ln;
    k0 = cc * 64 + lq * 8;
    src = (row < BHALF) ? (c_i + (size_t)row * DC) : (c_j + (size_t)(row - BHALF) * DC);
    dst = cbT + (size_t)i2 * 16;
  }
  floatx4 a0 = *(const floatx4*)(src + k0);
  floatx4 a1 = *(const floatx4*)(src + k0 + 4);
  floatx4 b0 = *(const floatx4*)(src + k0 + 32);
  floatx4 b1 = *(const floatx4*)(src + k0 + 36);
  uint4v o;
  o.x = pk4_e4m3(a0[0], a0[1], a0[2], a0[3]);
  o.y = pk4_e4m3(a1[0], a1[1], a1[2], a1[3]);
  o.z = pk4_e4m3(b0[0], b0[1], b0[2], b0[3]);
  o.w = pk4_e4m3(b1[0], b1[1], b1[2], b1[3]);
  *(uint4v*)dst = o;
}

// stage col-tile ct into LDS: wave w stages z chunk-group w; waves 0,1 stage c
__device__ __forceinline__ void stage_tile(const uint8_t* __restrict__ zbT,
                                           const uint8_t* __restrict__ cbT,
                                           uint8_t* zS, uint8_t* cS,
                                           int ct, int w, int lane) {
  const uint8_t* src = zbT + (((size_t)ct * 8 + w) * 64 + lane) * 16;
  __builtin_amdgcn_global_load_lds((const __attribute__((address_space(1))) void*)src,
                                   (__attribute__((address_space(3))) void*)(zS + w * 1024),
                                   16, 0, 0);
  if (w < 2) {
    const uint8_t* srcc = cbT + (((size_t)ct * 2 + w) * 64 + lane) * 16;
    __builtin_amdgcn_global_load_lds((const __attribute__((address_space(1))) void*)srcc,
                                     (__attribute__((address_space(3))) void*)(cS + w * 1024),
                                     16, 0, 0);
  }
}

// finalize one 128-row group g: negsum[row] = sum_{cb>=g} RP[row][cb] +
// sum_{rb<=g} CP[row][rb]; merge pos, reduce, one atomicAdd. Called by the
// block whose decrement took ctr[g] to 0 (all contributors release-fenced first).
__device__ void group_finalize(int g, const float* __restrict__ RP,
                               const float* __restrict__ CP,
                               const float* __restrict__ pos2,
                               float* __restrict__ out, float* colbuf,
                               int tid, int w, int lane) {
  __threadfence();   // acquire: pull remote RP/CP
  float acc = 0.0f;
  for (int rr = w; rr < 128; rr += 8) {
    const int row = g * 128 + rr;
    float v = 0.0f;
    if (lane >= g) v += RP[(size_t)row * 64 + lane];
    if (lane <= g) v += CP[(size_t)row * 64 + lane];
#pragma unroll
    for (int off = 1; off < 64; off <<= 1) v += __shfl_xor(v, off);
    if (lane == 0) {
      float pos  = pos2[row & (BHALF - 1)];
      float lneg = FIXM + __logf(v);
      float hi = fmaxf(lneg, pos), lo = fminf(lneg, pos);
      float lse = hi + __logf(1.0f + __expf(lo - hi));
      acc += lse - pos;
    }
  }
  __syncthreads();                     // colbuf free
  if (lane == 0) colbuf[w] = acc;
  __syncthreads();
  if (tid == 0) {
    float s = 0.0f;
#pragma unroll
    for (int i = 0; i < 8; ++i) s += colbuf[i];
    atomicAdd(out, s * (1.0f / NTOT));
  }
  __syncthreads();
}

// ---------------- fused symmetric flash-lse + group-completion finalize ----------------
// EXACT R13 math core (best: 47.4 us, no spill): 2080 upper-triangle 128x128
// blocks, 512 thr = 8 waves x 16 rows, ONE A-set/wave of K=128 MX-fp8 operands
// (~48 VGPR; R14 proved a second set spills at the (512,4) 128-reg cap).
// Tail: after RP/CP stores, release fence + ctr[rb]/ctr[cb] ACQ_REL decrements;
// the block that zeroes a counter finalizes that row-group (no spinning).
__launch_bounds__(512, 4)
__global__ void fused_kernel(const uint8_t* __restrict__ zbT, const uint8_t* __restrict__ cbT,
                             float* __restrict__ RP, float* __restrict__ CP,
                             const float* __restrict__ pos2, unsigned int* __restrict__ ctr,
                             float* __restrict__ out) {
  __shared__ __align__(16) uint8_t zS[2][8192];   // 2 x 8 KB
  __shared__ __align__(16) uint8_t cS[2][2048];   // 2 x 2 KB
  __shared__ float colbuf[8 * 128];               // 4 KB
  __shared__ int lastA, lastB;

  // triangular decode: t -> (rb, cb), rb <= cb, 2080 blocks
  const int t = blockIdx.x;
  const int u = 2079 - t;
  int k = (int)((__builtin_sqrtf(8.0f * (float)u + 1.0f) - 1.0f) * 0.5f);
  while ((k + 1) * (k + 2) / 2 <= u) ++k;
  while (k * (k + 1) / 2 > u) --k;
  const int j = u - k * (k + 1) / 2;
  const int rb = 63 - k;
  const int cb = 63 - j;
  const bool diagBlk = (rb == cb);
  const bool pairBlk = (cb == rb + 32);

  const int tid  = threadIdx.x;
  const int w    = tid >> 6;      // 0..7
  const int lane = tid & 63;
  const int lq   = lane >> 4;
  const int ln   = lane & 15;

  const int row_w = rb * 128 + w * 16;     // wave's 16 rows
  const int rt    = row_w >> 4;            // row-tile = rb*8 + w

  // A operands: z = 4 x v8i32 (kq windows), c = 1 x v8i32 (K=128 exactly)
  int8v a_z[4], a_c;
  {
    const uint8_t* p = zbT + ((size_t)rt * 8 * 64 + lane) * 16;
#pragma unroll
    for (int kq = 0; kq < 4; ++kq)
      a_z[kq] = mk8(*(const ulong2v*)(p + (size_t)(2 * kq) * 1024),
                    *(const ulong2v*)(p + (size_t)(2 * kq + 1) * 1024));
    const uint8_t* q = cbT + ((size_t)rt * 2 * 64 + lane) * 16;
    a_c = mk8(*(const ulong2v*)q, *(const ulong2v*)(q + 1024));
  }

  float l_[4] = {0.f, 0.f, 0.f, 0.f};

  const int ct_base = cb * 8;
  stage_tile(zbT, cbT, zS[0], cS[0], ct_base, w, lane);
  __syncthreads();

#pragma unroll
  for (int it = 0; it < 8; ++it) {
    const int cur = it & 1;
    if (it + 1 < 8)
      stage_tile(zbT, cbT, zS[cur ^ 1], cS[cur ^ 1], ct_base + it + 1, w, lane);

    float lcv = 0.0f;
    // wave-uniform skip: in diag blocks, tiles fully below this wave's rows
    if (!(diagBlk && it < w)) {
      const uint8_t* zb  = zS[cur];
      const uint8_t* cb_ = cS[cur];

      f32x4 ac = {0.f, 0.f, 0.f, 0.f};
      {
        const int8v b = mk8(*(const ulong2v*)(cb_ + lane * 16),
                            *(const ulong2v*)(cb_ + 1024 + lane * 16));
        ac = MFMAS(a_c, b, ac);
      }
      f32x4 az = {0.f, 0.f, 0.f, 0.f};
#pragma unroll
      for (int kq = 0; kq < 4; ++kq) {
        const int8v b = mk8(*(const ulong2v*)(zb + (2 * kq) * 1024 + lane * 16),
                            *(const ulong2v*)(zb + (2 * kq + 1) * 1024 + lane * 16));
        az = MFMAS(a_z[kq], b, az);
      }

      const int gc  = cb * 128 + it * 16 + ln;
      const int grb = row_w + lq * 4;
      const bool pairTile = pairBlk && (it == w);
#pragma unroll
      for (int r = 0; r < 4; ++r) {
        float tv = fmaxf(ac[r], TEMPV);
        float sv = az[r] * __builtin_amdgcn_rcpf(tv);
        float e  = __builtin_amdgcn_exp2f(__builtin_fmaf(sv, LOG2E, -FM2));
        if (diagBlk && gc <= grb + r) e = 0.0f;        // diag + lower half
        if (pairTile && ln == lq * 4 + r) e = 0.0f;    // pair exclusion
        l_[r] += e;
        lcv += e;
      }
    }

    // col partial for this tile: reduce over lq, store (unique slot, pre-barrier)
    float v = lcv;
    v += __shfl_xor(v, 16);
    v += __shfl_xor(v, 32);
    if (lq == 0) colbuf[w * 128 + it * 16 + ln] = v;

    __syncthreads();   // protects cur buffer; drains prefetch; orders colbuf
  }

  // row partials -> RP[row][cb] (xor offs 1..8 stay within the quad group)
#pragma unroll
  for (int r = 0; r < 4; ++r) {
    float ll = l_[r];
#pragma unroll
    for (int off = 1; off < 16; off <<= 1) ll += __shfl_xor(ll, off);
    if (ln == 0) RP[(size_t)(row_w + lq * 4 + r) * 64 + cb] = ll;
  }

  // col partials: sum the 8 per-wave rows of colbuf -> CP[col][rb]
  if (tid < 128) {
    float s = 0.0f;
#pragma unroll
    for (int ww = 0; ww < 8; ++ww) s += colbuf[ww * 128 + tid];
    CP[(size_t)(cb * 128 + tid) * 64 + rb] = s;
  }

  // ---- group-completion: decrement contributor counters; last block finalizes ----
  __threadfence();                 // release RP/CP stores (device scope)
  __syncthreads();                 // all stores issued before the decrement
  if (tid == 0) {
    lastA = 0; lastB = 0;
    unsigned int o1 = __hip_atomic_fetch_sub(&ctr[rb], 1u, __ATOMIC_ACQ_REL,
                                             __HIP_MEMORY_SCOPE_AGENT);
    if (o1 == 1u) lastA = 1;
    if (cb != rb) {
      unsigned int o2 = __hip_atomic_fetch_sub(&ctr[cb], 1u, __ATOMIC_ACQ_REL,
                                               __HIP_MEMORY_SCOPE_AGENT);
      if (o2 == 1u) lastB = 1;
    }
  }
  __syncthreads();
  if (lastA) group_finalize(rb, RP, CP, pos2, out, colbuf, tid, w, lane);
  if (lastB) group_finalize(cb, RP, CP, pos2, out, colbuf, tid, w, lane);
}

extern "C" void kernel_launch(void* const* d_in, const int* in_sizes, int n_in,
                              void* d_out, int out_size, void* d_ws, size_t ws_size,
                              hipStream_t stream) {
  const float* z_i = (const float*)d_in[0];
  const float* z_j = (const float*)d_in[1];
  const float* c_i = (const float*)d_in[2];
  const float* c_j = (const float*)d_in[3];

  uint8_t* zbT = (uint8_t*)d_ws;                        // 4 MB fp8 z (tiled)
  uint8_t* cbT = zbT + (size_t)NTOT * DZ;               // 1 MB fp8 c (tiled)
  float* RP   = (float*)(cbT + (size_t)NTOT * DC);      // 2 MB
  float* CP   = RP + (size_t)NTOT * 64;                 // 2 MB
  float* pos2 = CP + (size_t)NTOT * 64;                 // 16 KB
  unsigned int* ctr = (unsigned int*)(pos2 + BHALF);    // 64 x u32

  convert_kernel<<<1536, 256, 0, stream>>>(z_i, z_j, c_i, c_j, zbT, cbT,
                                           pos2, ctr, (float*)d_out);
  fused_kernel<<<2080, 512, 0, stream>>>(zbT, cbT, RP, CP, pos2, ctr, (float*)d_out);
}

// Round 16
// 126.594 us; speedup vs baseline: 5.6940x; 5.6940x over previous
//
#include <hip/hip_runtime.h>
#include <stdint.h>

#define NTOT 8192
#define BHALF 4096
#define DZ 512
#define DC 128
#define TEMPV 0.5f
#define FIXM 16.0f
#define LOG2E 1.44269504f
#define FM2 23.08312065f   // FIXM * LOG2E
#define SCALE1 0x7F7F7F7F  // e8m0 unit scales

typedef __attribute__((ext_vector_type(4))) float f32x4;
typedef __attribute__((ext_vector_type(4))) float floatx4;
typedef __attribute__((ext_vector_type(2))) unsigned long ulong2v;  // 16B chunk
typedef __attribute__((ext_vector_type(8))) int int8v;              // 32B MFMA operand
typedef __attribute__((ext_vector_type(4))) unsigned int uint4v;

#define MFMAS(a, b, c) \
  __builtin_amdgcn_mfma_scale_f32_16x16x128_f8f6f4((a), (b), (c), 0, 0, 0, SCALE1, 0, SCALE1)

__device__ __forceinline__ uint32_t pk4_e4m3(float f0, float f1, float f2, float f3) {
  int w = 0;
  w = __builtin_amdgcn_cvt_pk_fp8_f32(f0, f1, w, false);
  w = __builtin_amdgcn_cvt_pk_fp8_f32(f2, f3, w, true);
  return (uint32_t)w;
}

__device__ __forceinline__ int8v mk8(ulong2v lo, ulong2v hi) {
  int8v r;
  ((ulong2v*)&r)[0] = lo;
  ((ulong2v*)&r)[1] = hi;
  return r;
}

// ---------------- convert: fp32 -> fp8 e4m3 (frag-pair-tiled) + exact pos dots ----------------
// Blocks 0..1279: 16B chunk ((ct*KP+cc)*64+lane): bytes 0..7 = x[ct*16+ln][cc*64+lq*8..+8),
// bytes 8..15 same +32 in k. A-frag layout == B-frag layout; chunk-pair (2kq,2kq+1) =
// 32B K=128 MFMA operand (consistent k-permutation for A and B -> dot unaffected).
// Blocks 1280..1535: pos2[p] = 2*dot(z_i[p], z_j[p]) exact fp32.
__global__ void convert_kernel(const float* __restrict__ z_i, const float* __restrict__ z_j,
                               const float* __restrict__ c_i, const float* __restrict__ c_j,
                               uint8_t* __restrict__ zbT, uint8_t* __restrict__ cbT,
                               float* __restrict__ pos2, float* __restrict__ out) {
  const int ZC = NTOT * DZ / 16;   // 262144 chunks
  const int CC = NTOT * DC / 16;   // 65536

  if (blockIdx.x >= 1280) {
    if (blockIdx.x == 1280 && threadIdx.x == 0) out[0] = 0.0f;
    const int wv   = (blockIdx.x - 1280) * 4 + (threadIdx.x >> 6);
    const int lane = threadIdx.x & 63;
#pragma unroll
    for (int q = 0; q < 4; ++q) {
      const int p = wv * 4 + q;
      const float* a = z_i + (size_t)p * DZ + lane * 8;
      const float* b = z_j + (size_t)p * DZ + lane * 8;
      floatx4 a0 = *(const floatx4*)a, a1 = *(const floatx4*)(a + 4);
      floatx4 b0 = *(const floatx4*)b, b1 = *(const floatx4*)(b + 4);
      float d = a0[0]*b0[0] + a0[1]*b0[1] + a0[2]*b0[2] + a0[3]*b0[3]
              + a1[0]*b1[0] + a1[1]*b1[1] + a1[2]*b1[2] + a1[3]*b1[3];
#pragma unroll
      for (int off = 1; off < 64; off <<= 1) d += __shfl_xor(d, off);
      if (lane == 0) pos2[p] = 2.0f * d;
    }
    return;
  }

  int i = blockIdx.x * blockDim.x + threadIdx.x;
  const float* src;
  uint8_t* dst;
  int k0;
  if (i < ZC) {
    int lane = i & 63, g = i >> 6;
    int ct = g >> 3, cc = g & 7;
    int ln = lane & 15, lq = lane >> 4;
    int row = ct * 16 + ln;
    k0 = cc * 64 + lq * 8;
    src = (row < BHALF) ? (z_i + (size_t)row * DZ) : (z_j + (size_t)(row - BHALF) * DZ);
    dst = zbT + (size_t)i * 16;
  } else {
    int i2 = i - ZC;
    int lane = i2 & 63, g = i2 >> 6;
    int ct = g >> 1, cc = g & 1;
    int ln = lane & 15, lq = lane >> 4;
    int row = ct * 16 + ln;
    k0 = cc * 64 + lq * 8;
    src = (row < BHALF) ? (c_i + (size_t)row * DC) : (c_j + (size_t)(row - BHALF) * DC);
    dst = cbT + (size_t)i2 * 16;
  }
  floatx4 a0 = *(const floatx4*)(src + k0);
  floatx4 a1 = *(const floatx4*)(src + k0 + 4);
  floatx4 b0 = *(const floatx4*)(src + k0 + 32);
  floatx4 b1 = *(const floatx4*)(src + k0 + 36);
  uint4v o;
  o.x = pk4_e4m3(a0[0], a0[1], a0[2], a0[3]);
  o.y = pk4_e4m3(a1[0], a1[1], a1[2], a1[3]);
  o.z = pk4_e4m3(b0[0], b0[1], b0[2], b0[3]);
  o.w = pk4_e4m3(b1[0], b1[1], b1[2], b1[3]);
  *(uint4v*)dst = o;
}

// stage z col-tile ct into LDS: wave w stages chunk-group w (c is NOT staged —
// its B-operands are read directly from global: 1 MB L2-resident, coalesced)
__device__ __forceinline__ void stage_tile(const uint8_t* __restrict__ zbT,
                                           uint8_t* zS, int ct, int w, int lane) {
  const uint8_t* src = zbT + (((size_t)ct * 8 + w) * 64 + lane) * 16;
  __builtin_amdgcn_global_load_lds((const __attribute__((address_space(1))) void*)src,
                                   (__attribute__((address_space(3))) void*)(zS + w * 1024),
                                   16, 0, 0);
}

// ---------------- fused symmetric flash-lse: upper-triangle 128x128 blocks ----------------
// R13 core (best verified: 47.4 us, no spill) with ONE delta: c B-operands come
// straight from global (L1/L2) instead of LDS -> LDS pipe (the bottleneck,
// 40 B/entry) drops 20% and the c staging calls disappear. z stays in LDS
// (32 B/entry shared 8 ways — R4 proved global-only z thrashes L1).
// 2080 blocks, 512 thr = 8 waves x 16 rows, ONE A-set/wave of K=128 MX-fp8
// operands (~48 VGPR; R14: a second set spills at the (512,4) 128-reg cap).
// No atomics, no fences: plain stores RP[row][cb] / CP[col][rb] (R15: device-
// scope RMW tails on hot lines cost ~µs each and serialize — never again).
__launch_bounds__(512, 4)
__global__ void fused_kernel(const uint8_t* __restrict__ zbT, const uint8_t* __restrict__ cbT,
                             float* __restrict__ RP, float* __restrict__ CP) {
  __shared__ __align__(16) uint8_t zS[2][8192];   // 2 x 8 KB
  __shared__ float colbuf[8 * 128];               // 4 KB

  // triangular decode: t -> (rb, cb), rb <= cb, 2080 blocks
  const int t = blockIdx.x;
  const int u = 2079 - t;
  int k = (int)((__builtin_sqrtf(8.0f * (float)u + 1.0f) - 1.0f) * 0.5f);
  while ((k + 1) * (k + 2) / 2 <= u) ++k;
  while (k * (k + 1) / 2 > u) --k;
  const int j = u - k * (k + 1) / 2;
  const int rb = 63 - k;
  const int cb = 63 - j;
  const bool diagBlk = (rb == cb);
  const bool pairBlk = (cb == rb + 32);

  const int tid  = threadIdx.x;
  const int w    = tid >> 6;      // 0..7
  const int lane = tid & 63;
  const int lq   = lane >> 4;
  const int ln   = lane & 15;

  const int row_w = rb * 128 + w * 16;     // wave's 16 rows
  const int rt    = row_w >> 4;            // row-tile = rb*8 + w

  // A operands: z = 4 x v8i32 (kq windows), c = 1 x v8i32 (K=128 exactly)
  int8v a_z[4], a_c;
  {
    const uint8_t* p = zbT + ((size_t)rt * 8 * 64 + lane) * 16;
#pragma unroll
    for (int kq = 0; kq < 4; ++kq)
      a_z[kq] = mk8(*(const ulong2v*)(p + (size_t)(2 * kq) * 1024),
                    *(const ulong2v*)(p + (size_t)(2 * kq + 1) * 1024));
    const uint8_t* q = cbT + ((size_t)rt * 2 * 64 + lane) * 16;
    a_c = mk8(*(const ulong2v*)q, *(const ulong2v*)(q + 1024));
  }

  float l_[4] = {0.f, 0.f, 0.f, 0.f};

  const int ct_base = cb * 8;
  stage_tile(zbT, zS[0], ct_base, w, lane);
  __syncthreads();

#pragma unroll
  for (int it = 0; it < 8; ++it) {
    const int cur = it & 1;
    if (it + 1 < 8)
      stage_tile(zbT, zS[cur ^ 1], ct_base + it + 1, w, lane);

    const int ct = ct_base + it;
    float lcv = 0.0f;
    // wave-uniform skip: in diag blocks, tiles fully below this wave's rows
    if (!(diagBlk && it < w)) {
      const uint8_t* zb = zS[cur];

      f32x4 ac = {0.f, 0.f, 0.f, 0.f};
      {
        // c B-operand straight from global (coalesced 1 KB x2, L2-resident)
        const uint8_t* qc = cbT + (((size_t)ct * 2) * 64 + lane) * 16;
        const int8v b = mk8(*(const ulong2v*)qc, *(const ulong2v*)(qc + 1024));
        ac = MFMAS(a_c, b, ac);
      }
      f32x4 az = {0.f, 0.f, 0.f, 0.f};
#pragma unroll
      for (int kq = 0; kq < 4; ++kq) {
        const int8v b = mk8(*(const ulong2v*)(zb + (2 * kq) * 1024 + lane * 16),
                            *(const ulong2v*)(zb + (2 * kq + 1) * 1024 + lane * 16));
        az = MFMAS(a_z[kq], b, az);
      }

      const int gc  = cb * 128 + it * 16 + ln;
      const int grb = row_w + lq * 4;
      const bool pairTile = pairBlk && (it == w);
#pragma unroll
      for (int r = 0; r < 4; ++r) {
        float tv = fmaxf(ac[r], TEMPV);
        float sv = az[r] * __builtin_amdgcn_rcpf(tv);
        float e  = __builtin_amdgcn_exp2f(__builtin_fmaf(sv, LOG2E, -FM2));
        if (diagBlk && gc <= grb + r) e = 0.0f;        // diag + lower half
        if (pairTile && ln == lq * 4 + r) e = 0.0f;    // pair exclusion
        l_[r] += e;
        lcv += e;
      }
    }

    // col partial for this tile: reduce over lq, store (unique slot, pre-barrier)
    float v = lcv;
    v += __shfl_xor(v, 16);
    v += __shfl_xor(v, 32);
    if (lq == 0) colbuf[w * 128 + it * 16 + ln] = v;

    __syncthreads();   // protects cur buffer; drains prefetch; orders colbuf
  }

  // row partials -> RP[row][cb] (xor offs 1..8 stay within the quad group)
#pragma unroll
  for (int r = 0; r < 4; ++r) {
    float ll = l_[r];
#pragma unroll
    for (int off = 1; off < 16; off <<= 1) ll += __shfl_xor(ll, off);
    if (ln == 0) RP[(size_t)(row_w + lq * 4 + r) * 64 + cb] = ll;
  }

  // col partials: sum the 8 per-wave rows of colbuf -> CP[col][rb]
  if (tid < 128) {
    float s = 0.0f;
#pragma unroll
    for (int ww = 0; ww < 8; ++ww) s += colbuf[ww * 128 + tid];
    CP[(size_t)(cb * 128 + tid) * 64 + rb] = s;
  }
}

// ---------------- finalize: triangular partial merge + pos + reduction ----------------
// 512 blocks x 1024 thr; one wave per row. Row r (block R=r>>7): negsum =
// sum_{cb>=R} RP[r][cb] + sum_{rb<=R} CP[r][rb]  (coalesced 256B reads; 4 MB total).
__global__ void finalize_kernel(const float* __restrict__ RP, const float* __restrict__ CP,
                                const float* __restrict__ pos2, float* __restrict__ out) {
  const int tid  = threadIdx.x;
  const int w    = tid >> 6;
  const int lane = tid & 63;
  const int row  = blockIdx.x * 16 + w;
  const int R    = row >> 7;

  float v = 0.0f;
  if (lane >= R) v += RP[(size_t)row * 64 + lane];
  if (lane <= R) v += CP[(size_t)row * 64 + lane];
#pragma unroll
  for (int off = 1; off < 64; off <<= 1) v += __shfl_xor(v, off);

  __shared__ float red[16];
  if (lane == 0) {
    float pos  = pos2[row & (BHALF - 1)];
    float lneg = FIXM + __logf(v);
    float hi = fmaxf(lneg, pos), lo = fminf(lneg, pos);
    float lse = hi + __logf(1.0f + __expf(lo - hi));
    red[w] = lse - pos;
  }
  __syncthreads();
  if (tid == 0) {
    float s = 0.0f;
#pragma unroll
    for (int i = 0; i < 16; ++i) s += red[i];
    atomicAdd(out, s * (1.0f / NTOT));
  }
}

extern "C" void kernel_launch(void* const* d_in, const int* in_sizes, int n_in,
                              void* d_out, int out_size, void* d_ws, size_t ws_size,
                              hipStream_t stream) {
  const float* z_i = (const float*)d_in[0];
  const float* z_j = (const float*)d_in[1];
  const float* c_i = (const float*)d_in[2];
  const float* c_j = (const float*)d_in[3];

  uint8_t* zbT = (uint8_t*)d_ws;                        // 4 MB fp8 z (tiled)
  uint8_t* cbT = zbT + (size_t)NTOT * DZ;               // 1 MB fp8 c (tiled)
  float* RP   = (float*)(cbT + (size_t)NTOT * DC);      // 2 MB
  float* CP   = RP + (size_t)NTOT * 64;                 // 2 MB
  float* pos2 = CP + (size_t)NTOT * 64;                 // 16 KB

  convert_kernel<<<1536, 256, 0, stream>>>(z_i, z_j, c_i, c_j, zbT, cbT, pos2, (float*)d_out);
  fused_kernel<<<2080, 512, 0, stream>>>(zbT, cbT, RP, CP);
  finalize_kernel<<<512, 1024, 0, stream>>>(RP, CP, pos2, (float*)d_out);
}

// Round 17
// 121.005 us; speedup vs baseline: 5.9570x; 1.0462x over previous
//
#include <hip/hip_runtime.h>
#include <stdint.h>

#define NTOT 8192
#define BHALF 4096
#define DZ 512
#define DC 128
#define TEMPV 0.5f
#define FIXM 16.0f
#define LOG2E 1.44269504f
#define FM2 23.08312065f   // FIXM * LOG2E
#define SCALE1 0x7F7F7F7F  // e8m0 unit scales

typedef __attribute__((ext_vector_type(4))) float f32x4;
typedef __attribute__((ext_vector_type(4))) float floatx4;
typedef __attribute__((ext_vector_type(2))) unsigned long ulong2v;  // 16B chunk
typedef __attribute__((ext_vector_type(8))) int int8v;              // 32B MFMA operand
typedef __attribute__((ext_vector_type(4))) unsigned int uint4v;

// MX-scaled fp8 MFMA, K=128, unit scales. cbsz=0/blgp=0 -> FP8 e4m3 A and B.
#define MFMAS(a, b, c) \
  __builtin_amdgcn_mfma_scale_f32_16x16x128_f8f6f4((a), (b), (c), 0, 0, 0, SCALE1, 0, SCALE1)

__device__ __forceinline__ uint32_t pk4_e4m3(float f0, float f1, float f2, float f3) {
  int w = 0;
  w = __builtin_amdgcn_cvt_pk_fp8_f32(f0, f1, w, false);
  w = __builtin_amdgcn_cvt_pk_fp8_f32(f2, f3, w, true);
  return (uint32_t)w;
}

__device__ __forceinline__ int8v mk8(ulong2v lo, ulong2v hi) {
  int8v r;
  ((ulong2v*)&r)[0] = lo;
  ((ulong2v*)&r)[1] = hi;
  return r;
}

// ---------------- convert: fp32 -> fp8 e4m3 (frag-pair-tiled) + exact pos dots ----------------
// Blocks 0..1279: 16B chunk ((ct*KP+cc)*64+lane): bytes 0..7 = x[ct*16+ln][cc*64+lq*8..+8),
// bytes 8..15 same +32 in k. A-frag layout (row-tile ct) == B-frag layout (col-tile ct).
// Chunk-pair (2kq, 2kq+1) = the 32B/lane operand of the K=128 scaled MFMA (k-window
// [kq*128, kq*128+128) exactly; k-order inside the window is a consistent permutation
// for A and B -> dot product unaffected).
// Blocks 1280..1535: pos2[p] = 2*dot(z_i[p], z_j[p]) exact fp32 (t forced to 0.5 at pairs).
__global__ void convert_kernel(const float* __restrict__ z_i, const float* __restrict__ z_j,
                               const float* __restrict__ c_i, const float* __restrict__ c_j,
                               uint8_t* __restrict__ zbT, uint8_t* __restrict__ cbT,
                               float* __restrict__ pos2, float* __restrict__ out) {
  const int ZC = NTOT * DZ / 16;   // 262144 chunks
  const int CC = NTOT * DC / 16;   // 65536  (ZC+CC = 1280*256 exactly)

  if (blockIdx.x >= 1280) {
    if (blockIdx.x == 1280 && threadIdx.x == 0) out[0] = 0.0f;
    const int wv   = (blockIdx.x - 1280) * 4 + (threadIdx.x >> 6);  // 0..1023
    const int lane = threadIdx.x & 63;
#pragma unroll
    for (int q = 0; q < 4; ++q) {
      const int p = wv * 4 + q;
      const float* a = z_i + (size_t)p * DZ + lane * 8;
      const float* b = z_j + (size_t)p * DZ + lane * 8;
      floatx4 a0 = *(const floatx4*)a, a1 = *(const floatx4*)(a + 4);
      floatx4 b0 = *(const floatx4*)b, b1 = *(const floatx4*)(b + 4);
      float d = a0[0]*b0[0] + a0[1]*b0[1] + a0[2]*b0[2] + a0[3]*b0[3]
              + a1[0]*b1[0] + a1[1]*b1[1] + a1[2]*b1[2] + a1[3]*b1[3];
#pragma unroll
      for (int off = 1; off < 64; off <<= 1) d += __shfl_xor(d, off);
      if (lane == 0) pos2[p] = 2.0f * d;
    }
    return;
  }

  int i = blockIdx.x * blockDim.x + threadIdx.x;
  const float* src;
  uint8_t* dst;
  int k0;
  if (i < ZC) {
    int lane = i & 63, g = i >> 6;
    int ct = g >> 3, cc = g & 7;
    int ln = lane & 15, lq = lane >> 4;
    int row = ct * 16 + ln;
    k0 = cc * 64 + lq * 8;
    src = (row < BHALF) ? (z_i + (size_t)row * DZ) : (z_j + (size_t)(row - BHALF) * DZ);
    dst = zbT + (size_t)i * 16;
  } else {
    int i2 = i - ZC;
    int lane = i2 & 63, g = i2 >> 6;
    int ct = g >> 1, cc = g & 1;
    int ln = lane & 15, lq = lane >> 4;
    int row = ct * 16 + ln;
    k0 = cc * 64 + lq * 8;
    src = (row < BHALF) ? (c_i + (size_t)row * DC) : (c_j + (size_t)(row - BHALF) * DC);
    dst = cbT + (size_t)i2 * 16;
  }
  floatx4 a0 = *(const floatx4*)(src + k0);
  floatx4 a1 = *(const floatx4*)(src + k0 + 4);
  floatx4 b0 = *(const floatx4*)(src + k0 + 32);
  floatx4 b1 = *(const floatx4*)(src + k0 + 36);
  uint4v o;
  o.x = pk4_e4m3(a0[0], a0[1], a0[2], a0[3]);
  o.y = pk4_e4m3(a1[0], a1[1], a1[2], a1[3]);
  o.z = pk4_e4m3(b0[0], b0[1], b0[2], b0[3]);
  o.w = pk4_e4m3(b1[0], b1[1], b1[2], b1[3]);
  *(uint4v*)dst = o;
}

// stage col-tile ct into LDS: wave w stages z chunk-group w; waves 0,1 stage c
__device__ __forceinline__ void stage_tile(const uint8_t* __restrict__ zbT,
                                           const uint8_t* __restrict__ cbT,
                                           uint8_t* zS, uint8_t* cS,
                                           int ct, int w, int lane) {
  const uint8_t* src = zbT + (((size_t)ct * 8 + w) * 64 + lane) * 16;
  __builtin_amdgcn_global_load_lds((const __attribute__((address_space(1))) void*)src,
                                   (__attribute__((address_space(3))) void*)(zS + w * 1024),
                                   16, 0, 0);
  if (w < 2) {
    const uint8_t* srcc = cbT + (((size_t)ct * 2 + w) * 64 + lane) * 16;
    __builtin_amdgcn_global_load_lds((const __attribute__((address_space(1))) void*)srcc,
                                     (__attribute__((address_space(3))) void*)(cS + w * 1024),
                                     16, 0, 0);
  }
}

// ---------------- fused symmetric flash-lse: upper-triangle 128x128 blocks ----------------
// R13 verified optimum (fused 47.4 us): 2080 triangle blocks, 512 thr = 8 waves
// x 16 rows, ONE A-set/wave of K=128 MX-fp8 operands (~48 VGPR), LDS double-
// buffer with one barrier/iter and prefetch-after-barrier, (512,4).
// Locked-in rules from R14/R15/R16: no second A-set (spills: K=128 operands are
// 8 VGPR each); no device-scope RMW tails (cross-XCD serialization); c stays in
// LDS (global read loses the prefetch pipelining).
__launch_bounds__(512, 4)
__global__ void fused_kernel(const uint8_t* __restrict__ zbT, const uint8_t* __restrict__ cbT,
                             float* __restrict__ RP, float* __restrict__ CP) {
  __shared__ __align__(16) uint8_t zS[2][8192];   // 2 x 8 KB
  __shared__ __align__(16) uint8_t cS[2][2048];   // 2 x 2 KB
  __shared__ float colbuf[8 * 128];               // 4 KB

  // triangular decode: t -> (rb, cb), rb <= cb, 2080 blocks
  const int t = blockIdx.x;
  const int u = 2079 - t;
  int k = (int)((__builtin_sqrtf(8.0f * (float)u + 1.0f) - 1.0f) * 0.5f);
  while ((k + 1) * (k + 2) / 2 <= u) ++k;
  while (k * (k + 1) / 2 > u) --k;
  const int j = u - k * (k + 1) / 2;
  const int rb = 63 - k;
  const int cb = 63 - j;
  const bool diagBlk = (rb == cb);
  const bool pairBlk = (cb == rb + 32);

  const int tid  = threadIdx.x;
  const int w    = tid >> 6;      // 0..7
  const int lane = tid & 63;
  const int lq   = lane >> 4;
  const int ln   = lane & 15;

  const int row_w = rb * 128 + w * 16;     // wave's 16 rows
  const int rt    = row_w >> 4;            // row-tile = rb*8 + w

  // A operands: z = 4 x v8i32 (kq windows), c = 1 x v8i32 (K=128 exactly)
  int8v a_z[4], a_c;
  {
    const uint8_t* p = zbT + ((size_t)rt * 8 * 64 + lane) * 16;
#pragma unroll
    for (int kq = 0; kq < 4; ++kq)
      a_z[kq] = mk8(*(const ulong2v*)(p + (size_t)(2 * kq) * 1024),
                    *(const ulong2v*)(p + (size_t)(2 * kq + 1) * 1024));
    const uint8_t* q = cbT + ((size_t)rt * 2 * 64 + lane) * 16;
    a_c = mk8(*(const ulong2v*)q, *(const ulong2v*)(q + 1024));
  }

  float l_[4] = {0.f, 0.f, 0.f, 0.f};

  const int ct_base = cb * 8;
  stage_tile(zbT, cbT, zS[0], cS[0], ct_base, w, lane);
  __syncthreads();

#pragma unroll
  for (int it = 0; it < 8; ++it) {
    const int cur = it & 1;
    if (it + 1 < 8)
      stage_tile(zbT, cbT, zS[cur ^ 1], cS[cur ^ 1], ct_base + it + 1, w, lane);

    float lcv = 0.0f;
    // wave-uniform skip: in diag blocks, tiles fully below this wave's rows
    if (!(diagBlk && it < w)) {
      const uint8_t* zb  = zS[cur];
      const uint8_t* cb_ = cS[cur];

      f32x4 ac = {0.f, 0.f, 0.f, 0.f};
      {
        const int8v b = mk8(*(const ulong2v*)(cb_ + lane * 16),
                            *(const ulong2v*)(cb_ + 1024 + lane * 16));
        ac = MFMAS(a_c, b, ac);
      }
      f32x4 az = {0.f, 0.f, 0.f, 0.f};
#pragma unroll
      for (int kq = 0; kq < 4; ++kq) {
        const int8v b = mk8(*(const ulong2v*)(zb + (2 * kq) * 1024 + lane * 16),
                            *(const ulong2v*)(zb + (2 * kq + 1) * 1024 + lane * 16));
        az = MFMAS(a_z[kq], b, az);
      }

      const int gc  = cb * 128 + it * 16 + ln;
      const int grb = row_w + lq * 4;
      const bool pairTile = pairBlk && (it == w);
#pragma unroll
      for (int r = 0; r < 4; ++r) {
        float tv = fmaxf(ac[r], TEMPV);
        float sv = az[r] * __builtin_amdgcn_rcpf(tv);
        float e  = __builtin_amdgcn_exp2f(__builtin_fmaf(sv, LOG2E, -FM2));
        if (diagBlk && gc <= grb + r) e = 0.0f;        // diag + lower half
        if (pairTile && ln == lq * 4 + r) e = 0.0f;    // pair exclusion
        l_[r] += e;
        lcv += e;
      }
    }

    // col partial for this tile: reduce over lq, store (unique slot, pre-barrier)
    float v = lcv;
    v += __shfl_xor(v, 16);
    v += __shfl_xor(v, 32);
    if (lq == 0) colbuf[w * 128 + it * 16 + ln] = v;

    __syncthreads();   // protects cur buffer; drains prefetch; orders colbuf
  }

  // row partials -> RP[row][cb] (xor offs 1..8 stay within the quad group)
#pragma unroll
  for (int r = 0; r < 4; ++r) {
    float ll = l_[r];
#pragma unroll
    for (int off = 1; off < 16; off <<= 1) ll += __shfl_xor(ll, off);
    if (ln == 0) RP[(size_t)(row_w + lq * 4 + r) * 64 + cb] = ll;
  }

  // col partials: sum the 8 per-wave rows of colbuf -> CP[col][rb]
  if (tid < 128) {
    float s = 0.0f;
#pragma unroll
    for (int ww = 0; ww < 8; ++ww) s += colbuf[ww * 128 + tid];
    CP[(size_t)(cb * 128 + tid) * 64 + rb] = s;
  }
}

// ---------------- finalize: triangular partial merge + pos + reduction ----------------
// 512 blocks x 1024 thr; one wave per row. Row r (block R=r>>7): negsum =
// sum_{cb>=R} RP[r][cb] + sum_{rb<=R} CP[r][rb]  (coalesced 256B reads; 4 MB total).
__global__ void finalize_kernel(const float* __restrict__ RP, const float* __restrict__ CP,
                                const float* __restrict__ pos2, float* __restrict__ out) {
  const int tid  = threadIdx.x;
  const int w    = tid >> 6;
  const int lane = tid & 63;
  const int row  = blockIdx.x * 16 + w;
  const int R    = row >> 7;

  float v = 0.0f;
  if (lane >= R) v += RP[(size_t)row * 64 + lane];
  if (lane <= R) v += CP[(size_t)row * 64 + lane];
#pragma unroll
  for (int off = 1; off < 64; off <<= 1) v += __shfl_xor(v, off);

  __shared__ float red[16];
  if (lane == 0) {
    float pos  = pos2[row & (BHALF - 1)];
    float lneg = FIXM + __logf(v);
    float hi = fmaxf(lneg, pos), lo = fminf(lneg, pos);
    float lse = hi + __logf(1.0f + __expf(lo - hi));
    red[w] = lse - pos;
  }
  __syncthreads();
  if (tid == 0) {
    float s = 0.0f;
#pragma unroll
    for (int i = 0; i < 16; ++i) s += red[i];
    atomicAdd(out, s * (1.0f / NTOT));
  }
}

extern "C" void kernel_launch(void* const* d_in, const int* in_sizes, int n_in,
                              void* d_out, int out_size, void* d_ws, size_t ws_size,
                              hipStream_t stream) {
  const float* z_i = (const float*)d_in[0];
  const float* z_j = (const float*)d_in[1];
  const float* c_i = (const float*)d_in[2];
  const float* c_j = (const float*)d_in[3];

  uint8_t* zbT = (uint8_t*)d_ws;                        // 4 MB fp8 z (tiled)
  uint8_t* cbT = zbT + (size_t)NTOT * DZ;               // 1 MB fp8 c (tiled)
  float* RP   = (float*)(cbT + (size_t)NTOT * DC);      // 2 MB
  float* CP   = RP + (size_t)NTOT * 64;                 // 2 MB
  float* pos2 = CP + (size_t)NTOT * 64;                 // 16 KB

  convert_kernel<<<1536, 256, 0, stream>>>(z_i, z_j, c_i, c_j, zbT, cbT, pos2, (float*)d_out);
  fused_kernel<<<2080, 512, 0, stream>>>(zbT, cbT, RP, CP);
  finalize_kernel<<<512, 1024, 0, stream>>>(RP, CP, pos2, (float*)d_out);
}